// Round 5
// baseline (753.037 us; speedup 1.0000x reference)
//
#include <hip/hip_runtime.h>
#include <math.h>

#define VOCAB   50257
#define VP      50272      // vocab padded to 32*1571
#define NVT     1571       // vocab tiles of 32 rows
#define DM      256
#define INDIM   64
#define OUTDIM  64
#define NROWS   4096
#define SEQ     1024
#define NSLICE  8
#define TTOK    64         // tokens per block in fused kernel (2 waves x 32)
#define MARGIN  5e-3f
#define FLAGCAP 1024
#define EP      264        // LDS pitch used by prep/recheck tiles

typedef _Float16 f16;
typedef _Float16 half8 __attribute__((ext_vector_type(8)));
typedef _Float16 half4v __attribute__((ext_vector_type(4)));
typedef float floatx4 __attribute__((ext_vector_type(4)));

static __device__ __forceinline__ void gload_lds16(const f16* g, f16* l) {
    __builtin_amdgcn_global_load_lds(
        (const __attribute__((address_space(1))) void*)g,
        (__attribute__((address_space(3))) void*)l, 16, 0, 0);
}

// ---------------------------------------------------------------------------
// Kernel 1: encoder GEMM + posemb + LayerNorm -> hs (fp32, /16 folded),
// q_hi + q_lo (split fp16).
// ---------------------------------------------------------------------------
__global__ __launch_bounds__(256) void encode_ln_kernel(
    const float* __restrict__ x, const float* __restrict__ enc_w,
    const float* __restrict__ enc_b, const float* __restrict__ wpe,
    const float* __restrict__ ln_g, const float* __restrict__ ln_b,
    float* __restrict__ hs_out, f16* __restrict__ q_hi, f16* __restrict__ q_lo,
    int* flagcnt, int write_q)
{
    const int row = blockIdx.x;
    const int s   = row & (SEQ - 1);
    const int d   = threadIdx.x;

    __shared__ float xs[INDIM];
    __shared__ float w1[4], w2[4];

    if (d < INDIM) xs[d] = x[(size_t)row * INDIM + d];
    __syncthreads();

    const float4* wrow = (const float4*)(enc_w + (size_t)d * INDIM);
    float dot = 0.f;
#pragma unroll
    for (int i = 0; i < INDIM / 4; ++i) {
        float4 w4 = wrow[i];
        dot += w4.x * xs[i * 4 + 0] + w4.y * xs[i * 4 + 1]
             + w4.z * xs[i * 4 + 2] + w4.w * xs[i * 4 + 3];
    }
    float h = dot + enc_b[d] + wpe[(size_t)s * DM + d];

    float v1 = h, v2 = h * h;
#pragma unroll
    for (int mask = 1; mask < 64; mask <<= 1) {
        v1 += __shfl_xor(v1, mask, 64);
        v2 += __shfl_xor(v2, mask, 64);
    }
    if ((d & 63) == 0) { w1[d >> 6] = v1; w2[d >> 6] = v2; }
    __syncthreads();
    float S1 = w1[0] + w1[1] + w1[2] + w1[3];
    float S2 = w2[0] + w2[1] + w2[2] + w2[3];
    float mu  = S1 * (1.f / DM);
    float var = S2 * (1.f / DM) - mu * mu;
    float rs  = rsqrtf(var + 1e-5f);
    float hn  = (h - mu) * rs * ln_g[d] + ln_b[d];
    float hsv = hn * 0.0625f;
    hs_out[(size_t)row * DM + d] = hsv;
    if (write_q) {
        f16 hi = (f16)hsv;
        q_hi[(size_t)row * DM + d] = hi;
        q_lo[(size_t)row * DM + d] = (f16)(hsv - (float)hi);
    }
    if (row == 0 && d == 0 && write_q) *flagcnt = 0;
}

// ---------------------------------------------------------------------------
// Kernel 2: E (fp32) -> E_hi (fp16 row-major, VP rows) + E_T (fp16 [d][v]).
// ---------------------------------------------------------------------------
__global__ __launch_bounds__(256) void prep_emb(
    const float* __restrict__ emb, f16* __restrict__ e_hi, f16* __restrict__ e_t)
{
    const int v0 = blockIdx.x * 128;
    const int tid = threadIdx.x;
    __shared__ f16 tile[128][EP];

#pragma unroll 2
    for (int i = 0; i < 16; ++i) {
        int row = i * 8 + (tid >> 5);
        int col = (tid & 31) * 8;
        int v = v0 + row;
        half8 h;
        if (v < VOCAB) {
            const float* src = emb + (size_t)v * DM + col;
            float4 f0 = *(const float4*)(src);
            float4 f1 = *(const float4*)(src + 4);
            h[0]=(f16)f0.x; h[1]=(f16)f0.y; h[2]=(f16)f0.z; h[3]=(f16)f0.w;
            h[4]=(f16)f1.x; h[5]=(f16)f1.y; h[6]=(f16)f1.z; h[7]=(f16)f1.w;
        } else {
#pragma unroll
            for (int j = 0; j < 8; ++j) h[j] = (f16)0.f;
        }
        if (v < VP) *(half8*)(e_hi + (size_t)v * DM + col) = h;
        *(half8*)&tile[row][col] = h;
    }
    __syncthreads();

    const int cc = tid & 15;
    const bool ok = (v0 + cc * 8) < VP;
#pragma unroll 2
    for (int rr = 0; rr < 16; ++rr) {
        int d = rr * 16 + (tid >> 4);
        half8 w;
#pragma unroll
        for (int j = 0; j < 8; ++j) w[j] = tile[cc * 8 + j][d];
        if (ok) *(half8*)(e_t + (size_t)d * VP + v0 + cc * 8) = w;
    }
}

// ---------------------------------------------------------------------------
// Kernel 3: fused flash-style MFMA kernel, v2.
//  - 2 waves/block, 32 tokens/wave (64/block): every LDS fragment read feeds
//    2 MFMAs -> LDS ops per token halved vs round 4.
//  - E tiles staged via async global_load_lds (no VGPR round-trip). The LDS
//    image is XOR-swizzled in 16B chunks via the per-lane GLOBAL address:
//      ehi: chunk c of row v stored at phys p = c ^ (v&7)    (rows 512 B)
//      et : chunk c of row d stored at phys p = c ^ ((d>>1)&3) (rows 64 B)
//    -> all MFMA fragment reads hit 2 lanes/bank (free, m136).
//  - 512 blocks (64 token-tiles x 8 vocab slices), 2 blocks/CU, 69 KB LDS.
// ---------------------------------------------------------------------------
__global__ __launch_bounds__(128, 1) void fused_main(
    const f16* __restrict__ e_hi, const f16* __restrict__ e_t,
    const f16* __restrict__ q_hi,
    float* __restrict__ pO, float* __restrict__ pm1, float* __restrict__ pm2,
    float* __restrict__ pl, int* __restrict__ pi1)
{
    const int tid   = threadIdx.x;
    const int wave  = tid >> 6;
    const int lane  = tid & 63;
    const int m_    = lane & 15;
    const int quad  = lane >> 4;
    const int slice = blockIdx.x & 7;
    const int tt    = blockIdx.x >> 3;     // 64-token tile index (0..63)

    __shared__ f16 ehi_s[2][8192];         // 2 x 16 KB (32 v x 256 d, swizzled)
    __shared__ f16 et_s[2][8192];          // 2 x 16 KB (256 d x 32 v, swizzled)
    __shared__ f16 plds[2][32][40];        // per-wave private P buffer

    const int tok0 = tt * TTOK + wave * 32;

    // Q fragments for both token halves
    half8 qf[2][8];
#pragma unroll
    for (int th = 0; th < 2; ++th) {
        const f16* qb = q_hi + (size_t)(tok0 + th * 16 + m_) * DM + quad * 8;
#pragma unroll
        for (int s = 0; s < 8; ++s) qf[th][s] = *(const half8*)(qb + s * 32);
    }

    floatx4 O[2][16];
#pragma unroll
    for (int th = 0; th < 2; ++th)
#pragma unroll
        for (int i = 0; i < 16; ++i) { O[th][i][0]=0.f; O[th][i][1]=0.f; O[th][i][2]=0.f; O[th][i][3]=0.f; }
    float m1[2] = {-INFINITY, -INFINITY}, m2[2] = {-INFINITY, -INFINITY};
    float l[2]  = {0.f, 0.f};
    int   i1[2] = {0, 0};

    const int ntile = (NVT - slice + NSLICE - 1) / NSLICE;

    // ---- staging setup: wave0 stages ehi (A), wave1 stages et (B) ----
    int off[16];
    if (wave == 0) {
#pragma unroll
        for (int i = 0; i < 16; ++i) {
            int v_s = 2 * i + (lane >> 5);
            int c_s = (lane & 31) ^ (v_s & 7);
            off[i] = v_s * DM + c_s * 8;
        }
    } else {
        int c_s = (lane & 3) ^ ((lane >> 3) & 3);
#pragma unroll
        for (int i = 0; i < 16; ++i) {
            int d_s = i * 16 + (lane >> 2);
            off[i] = d_s * VP + c_s * 8;
        }
    }
    const f16* gbase = (wave == 0) ? (e_hi + (size_t)(slice * 32) * DM)
                                   : (e_t + slice * 32);
    const ptrdiff_t gstride = (wave == 0) ? (ptrdiff_t)NSLICE * 32 * DM
                                          : (ptrdiff_t)NSLICE * 32;
    f16* lbase = (wave == 0) ? &ehi_s[0][0] : &et_s[0][0];

    // prologue: stage tile 0 into buf 0
#pragma unroll
    for (int i = 0; i < 16; ++i)
        gload_lds16(gbase + off[i], lbase + i * 512);
    gbase += gstride;
    __syncthreads();

    for (int it = 0; it < ntile; ++it) {
        const int b  = it & 1;
        const int v0 = (slice + it * NSLICE) * 32;

        if (it + 1 < ntile) {
            f16* ldst = lbase + (b ^ 1) * 8192;
#pragma unroll
            for (int i = 0; i < 16; ++i)
                gload_lds16(gbase + off[i], ldst + i * 512);
            gbase += gstride;
        }

        // ---- GEMM1: S^T[v][tok], 2 v-halves x 2 tok-halves ----
        floatx4 sf[2][2];
#pragma unroll
        for (int vh = 0; vh < 2; ++vh)
#pragma unroll
            for (int th = 0; th < 2; ++th) {
                sf[vh][th][0]=0.f; sf[vh][th][1]=0.f; sf[vh][th][2]=0.f; sf[vh][th][3]=0.f;
            }
#pragma unroll
        for (int s = 0; s < 8; ++s) {
            const int c = 4 * s + quad;
            half8 a0 = *(const half8*)&ehi_s[b][m_ * DM + (c ^ (m_ & 7)) * 8];
            half8 a1 = *(const half8*)&ehi_s[b][(m_ + 16) * DM + (c ^ ((m_ + 16) & 7)) * 8];
            sf[0][0] = __builtin_amdgcn_mfma_f32_16x16x32_f16(a0, qf[0][s], sf[0][0], 0, 0, 0);
            sf[0][1] = __builtin_amdgcn_mfma_f32_16x16x32_f16(a0, qf[1][s], sf[0][1], 0, 0, 0);
            sf[1][0] = __builtin_amdgcn_mfma_f32_16x16x32_f16(a1, qf[0][s], sf[1][0], 0, 0, 0);
            sf[1][1] = __builtin_amdgcn_mfma_f32_16x16x32_f16(a1, qf[1][s], sf[1][1], 0, 0, 0);
        }
        if (v0 + 32 > VOCAB) {
#pragma unroll
            for (int vh = 0; vh < 2; ++vh)
#pragma unroll
                for (int r = 0; r < 4; ++r)
                    if (v0 + vh * 16 + quad * 4 + r >= VOCAB) {
                        sf[vh][0][r] = -INFINITY;
                        sf[vh][1][r] = -INFINITY;
                    }
        }

        // ---- per-token-half: top-2 + online softmax + P ----
        half8 a2[2];
#pragma unroll
        for (int th = 0; th < 2; ++th) {
            float t1 = -INFINITY, t2 = -INFINITY; int ti = 0;
#pragma unroll
            for (int vh = 0; vh < 2; ++vh)
#pragma unroll
                for (int r = 0; r < 4; ++r) {
                    float sv = sf[vh][th][r];
                    int vg = v0 + vh * 16 + quad * 4 + r;
                    t2 = fmaxf(t2, fminf(t1, sv));
                    ti = (sv > t1) ? vg : ti;
                    t1 = fmaxf(t1, sv);
                }
#pragma unroll
            for (int offc = 16; offc <= 32; offc += 16) {
                float o1 = __shfl_xor(t1, offc);
                float o2 = __shfl_xor(t2, offc);
                int   oi = __shfl_xor(ti, offc);
                t2 = fmaxf(fmaxf(t2, o2), fminf(t1, o1));
                ti = (o1 > t1) ? oi : ti;
                t1 = fmaxf(t1, o1);
            }

            float m1n = fmaxf(m1[th], t1);
            bool upd = (t1 > m1[th]);
            m2[th] = fmaxf(fmaxf(m2[th], t2), fminf(m1[th], t1));
            i1[th] = upd ? ti : i1[th];
            if (__any(upd)) {
                float c = __expf(m1[th] - m1n);
                l[th] *= c;
                float co[4];
#pragma unroll
                for (int r = 0; r < 4; ++r) co[r] = __shfl(c, (quad << 2) + r);
#pragma unroll
                for (int nt = 0; nt < 16; ++nt)
#pragma unroll
                    for (int r = 0; r < 4; ++r) O[th][nt][r] *= co[r];
            }
            m1[th] = m1n;

            float ls = 0.f;
            half4v hp[2];
#pragma unroll
            for (int vh = 0; vh < 2; ++vh)
#pragma unroll
                for (int r = 0; r < 4; ++r) {
                    float e = __expf(sf[vh][th][r] - m1n);
                    ls += e;
                    hp[vh][r] = (f16)e;
                }
            ls += __shfl_xor(ls, 16);
            ls += __shfl_xor(ls, 32);
            l[th] += ls;

            *(half4v*)(&plds[wave][th * 16 + m_][quad * 4])      = hp[0];
            *(half4v*)(&plds[wave][th * 16 + m_][16 + quad * 4]) = hp[1];
        }
        __asm__ volatile("s_waitcnt lgkmcnt(0)" ::: "memory");
#pragma unroll
        for (int th = 0; th < 2; ++th)
            a2[th] = *(const half8*)(&plds[wave][th * 16 + m_][quad * 8]);

        // ---- GEMM2: O[tok][d] += P . E ; each B-read feeds both halves ----
#pragma unroll
        for (int nt = 0; nt < 16; ++nt) {
            const int d = nt * 16 + m_;
            half8 b2 = *(const half8*)&et_s[b][d * 32 + (quad ^ ((d >> 1) & 3)) * 8];
            O[0][nt] = __builtin_amdgcn_mfma_f32_16x16x32_f16(a2[0], b2, O[0][nt], 0, 0, 0);
            O[1][nt] = __builtin_amdgcn_mfma_f32_16x16x32_f16(a2[1], b2, O[1][nt], 0, 0, 0);
        }

        __syncthreads();
    }

    // ---- write per-slice partials ----
#pragma unroll
    for (int th = 0; th < 2; ++th) {
        float* ob = pO + ((size_t)slice * NROWS + tok0 + th * 16) * DM;
#pragma unroll
        for (int nt = 0; nt < 16; ++nt)
#pragma unroll
            for (int r = 0; r < 4; ++r)
                ob[(size_t)(quad * 4 + r) * DM + nt * 16 + m_] = O[th][nt][r];
    }
    if (lane < 16) {
#pragma unroll
        for (int th = 0; th < 2; ++th) {
            const int idx = slice * NROWS + tok0 + th * 16 + lane;
            pm1[idx] = m1[th];
            pm2[idx] = m2[th];
            pl [idx] = l[th];
            pi1[idx] = i1[th];
        }
    }
}

// ---------------------------------------------------------------------------
// Kernel 4: merge slices, approximate argmax + margin flags, decoder.
// ---------------------------------------------------------------------------
__global__ __launch_bounds__(256) void merge_decode(
    const float* __restrict__ pO, const float* __restrict__ pm1,
    const float* __restrict__ pm2, const float* __restrict__ pl,
    const int* __restrict__ pi1,
    const float* __restrict__ dec_w, const float* __restrict__ dec_b,
    float* __restrict__ out, float* __restrict__ amax_out,
    unsigned long long* __restrict__ amax64, int* flagcnt, int* flaglist,
    int* __restrict__ flbyte)
{
    const int tt  = blockIdx.x;
    const int tid = threadIdx.x;
    __shared__ float q_s[16][DM];
    __shared__ float sc[NSLICE][16];
    __shared__ float lI[16];

    if (tid < 16) {
        const int row = tt * 16 + tid;
        float M = -INFINITY, M2 = -INFINITY; int win = 0;
        for (int s = 0; s < NSLICE; ++s) {
            float v = pm1[s * NROWS + row];
            if (v > M) { M2 = M; M = v; win = s; }
            else M2 = fmaxf(M2, v);
        }
        for (int s = 0; s < NSLICE; ++s)
            M2 = fmaxf(M2, pm2[s * NROWS + row]);
        amax_out[row] = (float)pi1[win * NROWS + row];
        amax64[row] = 0ull;
        int fl = (M - M2) < MARGIN;
        flbyte[row] = fl;
        if (fl) {
            int pos = atomicAdd(flagcnt, 1);
            if (pos < FLAGCAP) flaglist[pos] = row;
        }
        float lt = 0.f;
        for (int s = 0; s < NSLICE; ++s) {
            float e = __expf(pm1[s * NROWS + row] - M);
            sc[s][tid] = e;
            lt += pl[s * NROWS + row] * e;
        }
        lI[tid] = 1.f / lt;
    }
    __syncthreads();
    {
        const int m = tid >> 4, d0 = (tid & 15) * 16;
        const int row = tt * 16 + m;
        for (int d = d0; d < d0 + 16; ++d) {
            float a = 0.f;
            for (int s = 0; s < NSLICE; ++s)
                a += pO[((size_t)s * NROWS + row) * DM + d] * sc[s][m];
            q_s[m][d] = a * lI[m];
        }
    }
    __syncthreads();
    {
        const int o = tid & 63;
        const float4* wp = (const float4*)(dec_w + (size_t)o * DM);
#pragma unroll
        for (int k = 0; k < 4; ++k) {
            const int m = (tid >> 6) + k * 4;
            const float4* qp = (const float4*)&q_s[m][0];
            float acc = 0.f;
            for (int d4 = 0; d4 < DM / 4; ++d4) {
                float4 w = wp[d4], q = qp[d4];
                acc += w.x * q.x + w.y * q.y + w.z * q.z + w.w * q.w;
            }
            out[(size_t)(tt * 16 + m) * OUTDIM + o] = acc + dec_b[o];
        }
    }
}

// ---------------------------------------------------------------------------
// Kernel 5a: pack flagged rows' q_hi/q_lo densely.
// ---------------------------------------------------------------------------
__global__ __launch_bounds__(256) void gather_flagged(
    const f16* __restrict__ q_hi, const f16* __restrict__ q_lo,
    const int* __restrict__ flagcnt, const int* __restrict__ flaglist,
    f16* __restrict__ qg)
{
    int cnt = *flagcnt; if (cnt > FLAGCAP) cnt = FLAGCAP;
    const int j = blockIdx.x;
    if (j >= cnt) return;
    const int row = flaglist[j];
    const int t = threadIdx.x;
    qg[(size_t)j * 512 + t]       = q_hi[(size_t)row * DM + t];
    qg[(size_t)j * 512 + 256 + t] = q_lo[(size_t)row * DM + t];
}

// ---------------------------------------------------------------------------
// Kernel 5b: split-f16 MFMA recheck (4 cross products ~ fp32 exact).
// ---------------------------------------------------------------------------
__global__ __launch_bounds__(64) void recheck_rows(
    const float* __restrict__ emb, const f16* __restrict__ qg,
    const int* __restrict__ flagcnt, const int* __restrict__ flaglist,
    unsigned long long* __restrict__ amax64)
{
    int cnt = *flagcnt; if (cnt > FLAGCAP) cnt = FLAGCAP;
    if (cnt == 0) return;
    const int v0   = blockIdx.x * 32;
    const int lane = threadIdx.x;
    const int m_   = lane & 15;
    const int quad = lane >> 4;

    __shared__ f16 ehi[32][EP];
    __shared__ f16 elo[32][EP];

    for (int i = 0; i < 32; ++i) {
        const int v = v0 + i;
        float4 f = (v < VOCAB) ? *(const float4*)(emb + (size_t)v * DM + lane * 4)
                               : make_float4(0.f, 0.f, 0.f, 0.f);
        half4v hh, hl;
        hh[0]=(f16)f.x; hh[1]=(f16)f.y; hh[2]=(f16)f.z; hh[3]=(f16)f.w;
        hl[0]=(f16)(f.x-(float)hh[0]); hl[1]=(f16)(f.y-(float)hh[1]);
        hl[2]=(f16)(f.z-(float)hh[2]); hl[3]=(f16)(f.w-(float)hh[3]);
        *(half4v*)&ehi[i][lane * 4] = hh;
        *(half4v*)&elo[i][lane * 4] = hl;
    }
    __asm__ volatile("s_waitcnt lgkmcnt(0)" ::: "memory");

    for (int c0 = 0; c0 < cnt; c0 += 16) {
        const bool haveb = (c0 + m_) < cnt;
        const int fidx = haveb ? (c0 + m_) : 0;

        half8 bh[8], bl[8];
        const f16* qb = qg + (size_t)fidx * 512 + quad * 8;
#pragma unroll
        for (int s = 0; s < 8; ++s) {
            bh[s] = *(const half8*)(qb + s * 32);
            bl[s] = *(const half8*)(qb + 256 + s * 32);
        }

        floatx4 C0, C1;
        C0[0]=0.f; C0[1]=0.f; C0[2]=0.f; C0[3]=0.f;
        C1[0]=0.f; C1[1]=0.f; C1[2]=0.f; C1[3]=0.f;
#pragma unroll
        for (int s = 0; s < 8; ++s) {
            half8 ah0 = *(const half8*)&ehi[m_][quad * 8 + 32 * s];
            half8 al0 = *(const half8*)&elo[m_][quad * 8 + 32 * s];
            half8 ah1 = *(const half8*)&ehi[m_ + 16][quad * 8 + 32 * s];
            half8 al1 = *(const half8*)&elo[m_ + 16][quad * 8 + 32 * s];
            C0 = __builtin_amdgcn_mfma_f32_16x16x32_f16(ah0, bh[s], C0, 0, 0, 0);
            C0 = __builtin_amdgcn_mfma_f32_16x16x32_f16(ah0, bl[s], C0, 0, 0, 0);
            C0 = __builtin_amdgcn_mfma_f32_16x16x32_f16(al0, bh[s], C0, 0, 0, 0);
            C0 = __builtin_amdgcn_mfma_f32_16x16x32_f16(al0, bl[s], C0, 0, 0, 0);
            C1 = __builtin_amdgcn_mfma_f32_16x16x32_f16(ah1, bh[s], C1, 0, 0, 0);
            C1 = __builtin_amdgcn_mfma_f32_16x16x32_f16(ah1, bl[s], C1, 0, 0, 0);
            C1 = __builtin_amdgcn_mfma_f32_16x16x32_f16(al1, bh[s], C1, 0, 0, 0);
            C1 = __builtin_amdgcn_mfma_f32_16x16x32_f16(al1, bl[s], C1, 0, 0, 0);
        }

        float bv = -INFINITY; int bi = 0;
#pragma unroll
        for (int r = 0; r < 4; ++r) {
            int v = v0 + quad * 4 + r;
            float val = (v < VOCAB) ? C0[r] : -INFINITY;
            if (val > bv) { bv = val; bi = v; }
            int v2 = v + 16;
            float val2 = (v2 < VOCAB) ? C1[r] : -INFINITY;
            if (val2 > bv) { bv = val2; bi = v2; }
        }
#pragma unroll
        for (int offc = 16; offc <= 32; offc += 16) {
            float ov = __shfl_xor(bv, offc);
            int   oi = __shfl_xor(bi, offc);
            if (ov > bv || (ov == bv && oi < bi)) { bv = ov; bi = oi; }
        }
        if (quad == 0 && haveb) {
            unsigned u = __float_as_uint(bv);
            u = (u & 0x80000000u) ? ~u : (u | 0x80000000u);
            unsigned long long key =
                ((unsigned long long)u << 32) | (unsigned)(~bi);
            atomicMax(&amax64[flaglist[fidx]], key);
        }
    }
}

__global__ void finalize_amax(const int* __restrict__ flbyte,
                              const unsigned long long* __restrict__ amax64,
                              float* __restrict__ amax_out)
{
    int row = blockIdx.x * 256 + threadIdx.x;
    if (row >= NROWS) return;
    if (flbyte[row]) {
        unsigned long long u = amax64[row];
        if (u) {
            unsigned idx = ~(unsigned)(u & 0xffffffffu);
            amax_out[row] = (float)idx;
        }
    }
}

// ---------------------------------------------------------------------------
// Fallback (round-1 VALU kernel) if ws_size is too small.
// ---------------------------------------------------------------------------
#define RPB 4
__global__ __launch_bounds__(256, 2) void fused_softmax_quant_kernel(
    const float* __restrict__ emb, const float* __restrict__ hs,
    const float* __restrict__ dec_w, const float* __restrict__ dec_b,
    float* __restrict__ out, float* __restrict__ amax_out)
{
    const int tid  = threadIdx.x;
    const int g    = tid >> 4;
    const int q    = tid & 15;
    const int row0 = blockIdx.x * RPB;

    __shared__ __align__(16) float q_lds[RPB][DM];
    __shared__ float sm[16][RPB], sl[16][RPB];
    __shared__ int   sam[16][RPB];
    __shared__ float sLf[RPB];

    for (int i = tid; i < RPB * DM; i += 256) (&q_lds[0][0])[i] = 0.f;

    float4 hsr[RPB][4];
#pragma unroll
    for (int r = 0; r < RPB; ++r)
#pragma unroll
        for (int o = 0; o < 4; ++o)
            hsr[r][o] = *(const float4*)(hs + (size_t)(row0 + r) * DM + o * 64 + q * 4);

    float m[RPB], l[RPB];
    int   am[RPB];
    float4 acc[RPB][4];
#pragma unroll
    for (int r = 0; r < RPB; ++r) {
        m[r] = -INFINITY; l[r] = 0.f; am[r] = 0;
#pragma unroll
        for (int o = 0; o < 4; ++o) acc[r][o] = make_float4(0.f, 0.f, 0.f, 0.f);
    }

    float ecur[16], enxt[16];
    {
        size_t b0 = (size_t)g * DM + q * 4;
#pragma unroll
        for (int o = 0; o < 4; ++o)
            *(float4*)(enxt + o * 4) = *(const float4*)(emb + b0 + o * 64);
    }

#pragma unroll 1
    for (int v = g; v < VOCAB; v += 16) {
#pragma unroll
        for (int j = 0; j < 16; ++j) ecur[j] = enxt[j];
        int vn = (v + 16 < VOCAB) ? v + 16 : v;
        size_t bn = (size_t)vn * DM + q * 4;
#pragma unroll
        for (int o = 0; o < 4; ++o)
            *(float4*)(enxt + o * 4) = *(const float4*)(emb + bn + o * 64);

        float part[RPB];
#pragma unroll
        for (int r = 0; r < RPB; ++r) {
            const float* hp = (const float*)&hsr[r][0];
            float t = 0.f;
#pragma unroll
            for (int j = 0; j < 16; ++j) t += ecur[j] * hp[j];
            part[r] = t;
        }
#pragma unroll
        for (int mask = 8; mask >= 1; mask >>= 1)
#pragma unroll
            for (int r = 0; r < RPB; ++r)
                part[r] += __shfl_xor(part[r], mask, 16);

#pragma unroll
        for (int r = 0; r < RPB; ++r) {
            float lg = part[r];
            float* ap = (float*)&acc[r][0];
            if (lg > m[r]) {
                float c = __expf(m[r] - lg);
                m[r] = lg; am[r] = v;
                l[r] = l[r] * c + 1.f;
#pragma unroll
                for (int j = 0; j < 16; ++j) ap[j] = ap[j] * c + ecur[j];
            } else {
                float p = __expf(lg - m[r]);
                l[r] += p;
#pragma unroll
                for (int j = 0; j < 16; ++j) ap[j] += p * ecur[j];
            }
        }
    }

    if (q == 0) {
#pragma unroll
        for (int r = 0; r < RPB; ++r) { sm[g][r] = m[r]; sl[g][r] = l[r]; sam[g][r] = am[r]; }
    }
    __syncthreads();

    float wgt[RPB], Lr[RPB];
    int   A[RPB];
#pragma unroll
    for (int r = 0; r < RPB; ++r) {
        float M = -INFINITY; int a = 0;
        for (int gg = 0; gg < 16; ++gg) {
            float mv = sm[gg][r];
            if (mv > M) { M = mv; a = sam[gg][r]; }
        }
        float L = 0.f;
        for (int gg = 0; gg < 16; ++gg) L += sl[gg][r] * __expf(sm[gg][r] - M);
        wgt[r] = __expf(m[r] - M);
        Lr[r] = L; A[r] = a;
    }

#pragma unroll
    for (int r = 0; r < RPB; ++r) {
        const float* ap = (const float*)&acc[r][0];
#pragma unroll
        for (int j = 0; j < 16; ++j) {
            float vs = ap[j] * wgt[r];
            vs += __shfl_xor(vs, 16, 64);
            vs += __shfl_xor(vs, 32, 64);
            if ((g & 3) == 0) {
                int o = j >> 2, c = j & 3;
                atomicAdd(&q_lds[r][o * 64 + q * 4 + c], vs);
            }
        }
    }
    if (tid == 0) {
#pragma unroll
        for (int r = 0; r < RPB; ++r) {
            sLf[r] = Lr[r];
            amax_out[row0 + r] = (float)A[r];
        }
    }
    __syncthreads();

    {
        const int r = tid >> 6, o = tid & 63;
        const float4* dwp = (const float4*)(dec_w + (size_t)o * DM);
        const float4* qp  = (const float4*)&q_lds[r][0];
        float s = 0.f;
#pragma unroll 8
        for (int d4 = 0; d4 < DM / 4; ++d4) {
            float4 wv = dwp[d4];
            float4 qv = qp[d4];
            s += wv.x * qv.x + wv.y * qv.y + wv.z * qv.z + wv.w * qv.w;
        }
        s = s / sLf[r] + dec_b[o];
        out[(size_t)(row0 + r) * OUTDIM + o] = s;
    }
}

extern "C" void kernel_launch(void* const* d_in, const int* in_sizes, int n_in,
                              void* d_out, int out_size, void* d_ws, size_t ws_size,
                              hipStream_t stream)
{
    const float* x     = (const float*)d_in[0];
    const float* emb   = (const float*)d_in[1];
    const float* wpe   = (const float*)d_in[2];
    const float* enc_w = (const float*)d_in[3];
    const float* enc_b = (const float*)d_in[4];
    const float* ln_g  = (const float*)d_in[5];
    const float* ln_b  = (const float*)d_in[6];
    const float* dec_w = (const float*)d_in[7];
    const float* dec_b = (const float*)d_in[8];

    float* out      = (float*)d_out;
    float* amax_out = out + (size_t)NROWS * OUTDIM;

    char* w = (char*)d_ws;
    size_t off = 0;
    float* hs = (float*)(w + off);          off += (size_t)NROWS * DM * 4;
    f16* q_hi = (f16*)(w + off);            off += (size_t)NROWS * DM * 2;
    f16* q_lo = (f16*)(w + off);            off += (size_t)NROWS * DM * 2;
    f16* e_hi = (f16*)(w + off);            off += (size_t)VP * DM * 2;
    f16* e_t  = (f16*)(w + off);            off += (size_t)DM * VP * 2;
    float* pO = (float*)(w + off);          off += (size_t)NSLICE * NROWS * DM * 4;
    float* pm1 = (float*)(w + off);         off += (size_t)NSLICE * NROWS * 4;
    float* pm2 = (float*)(w + off);         off += (size_t)NSLICE * NROWS * 4;
    float* pl  = (float*)(w + off);         off += (size_t)NSLICE * NROWS * 4;
    int*   pi1 = (int*)(w + off);           off += (size_t)NSLICE * NROWS * 4;
    unsigned long long* amax64 = (unsigned long long*)(w + off); off += (size_t)NROWS * 8;
    int* flagcnt  = (int*)(w + off);        off += 256;
    int* flaglist = (int*)(w + off);        off += FLAGCAP * 4;
    int* flbyte   = (int*)(w + off);        off += (size_t)NROWS * 4;
    f16* qg       = (f16*)(w + off);        off += (size_t)FLAGCAP * 512 * 2;

    const bool full = (ws_size >= off);

    encode_ln_kernel<<<NROWS, 256, 0, stream>>>(x, enc_w, enc_b, wpe, ln_g, ln_b,
                                                hs, q_hi, q_lo, flagcnt, full ? 1 : 0);
    if (full) {
        prep_emb<<<(VP + 127) / 128, 256, 0, stream>>>(emb, e_hi, e_t);
        fused_main<<<(NROWS / TTOK) * NSLICE, 128, 0, stream>>>(e_hi, e_t, q_hi,
                                                                pO, pm1, pm2, pl, pi1);
        merge_decode<<<NROWS / 16, 256, 0, stream>>>(pO, pm1, pm2, pl, pi1, dec_w, dec_b,
                                                     out, amax_out, amax64, flagcnt,
                                                     flaglist, flbyte);
        gather_flagged<<<FLAGCAP, 256, 0, stream>>>(q_hi, q_lo, flagcnt, flaglist, qg);
        recheck_rows<<<NVT, 64, 0, stream>>>(emb, qg, flagcnt, flaglist, amax64);
        finalize_amax<<<(NROWS + 255) / 256, 256, 0, stream>>>(flbyte, amax64, amax_out);
    } else {
        fused_softmax_quant_kernel<<<NROWS / RPB, 256, 0, stream>>>(emb, hs, dec_w,
                                                                    dec_b, out, amax_out);
    }
}